// Round 6
// baseline (466.823 us; speedup 1.0000x reference)
//
#include <hip/hip_runtime.h>
#include <hip/hip_bf16.h>
#include <stdint.h>

// Problem constants: B=2, T=2048, D=2048, H=16, HKV=4, HD=128
#define B_    2
#define T_    2048
#define D_    2048
#define H_    16
#define HKV_  4
#define HD_   128
#define BT_   (B_ * T_)            // 4096
#define QD_   2048                 // H*HD
#define KVD_  512                  // HKV*HD

typedef float  f32x4 __attribute__((ext_vector_type(4)));
typedef short  s16x8 __attribute__((ext_vector_type(8)));   // 8 bf16 (4 VGPRs) MFMA operand
typedef unsigned short us;

__device__ __forceinline__ us f2bf(float f) {
    unsigned int u = __builtin_bit_cast(unsigned int, f);
    u += 0x7FFFu + ((u >> 16) & 1u);              // RNE (finite values only)
    return (us)(u >> 16);
}
__device__ __forceinline__ float bf2f(us s) {
    unsigned int u = ((unsigned int)s) << 16;
    return __builtin_bit_cast(float, u);
}
__device__ __forceinline__ unsigned pack2(float a, float b) {
    return (unsigned)f2bf(a) | ((unsigned)f2bf(b) << 16);
}

#define GLOBAL_AS __attribute__((address_space(1)))
#define LDS_AS    __attribute__((address_space(3)))

// async global->LDS, 16B per lane. LDS dest = wave-uniform base + lane*16.
__device__ __forceinline__ void gload16(const void* g, void* l) {
    __builtin_amdgcn_global_load_lds((const GLOBAL_AS uint32_t*)g,
                                     (LDS_AS uint32_t*)l, 16, 0, 0);
}

// ---------------------------------------------------------------------------
// Weight transpose+convert: w fp32 [K][N] -> wt bf16 [N][K]
// ---------------------------------------------------------------------------
__global__ __launch_bounds__(256)
void wtrans(const float* __restrict__ w, us* __restrict__ wt, int K, int N) {
    __shared__ float t[32][33];
    const int k0 = blockIdx.x * 32, n0 = blockIdx.y * 32;
    const int tid = threadIdx.x;
    const int r = tid >> 3, c4 = (tid & 7) << 2;
    const float4 v = *(const float4*)&w[(size_t)(k0 + r) * N + n0 + c4];
    t[r][c4 + 0] = v.x; t[r][c4 + 1] = v.y; t[r][c4 + 2] = v.z; t[r][c4 + 3] = v.w;
    __syncthreads();
    ushort4 o;
    o.x = f2bf(t[c4 + 0][r]); o.y = f2bf(t[c4 + 1][r]);
    o.z = f2bf(t[c4 + 2][r]); o.w = f2bf(t[c4 + 3][r]);
    *(ushort4*)&wt[(size_t)(n0 + r) * K + k0 + c4] = o;
}

// ---------------------------------------------------------------------------
// x fp32 -> bf16 (8 elems/thread)
// ---------------------------------------------------------------------------
__global__ __launch_bounds__(256)
void cvt_bf16(const float* __restrict__ x, us* __restrict__ xb, int n8) {
    const int i = blockIdx.x * 256 + threadIdx.x;
    if (i >= n8) return;
    const float4 a = ((const float4*)x)[i * 2];
    const float4 b = ((const float4*)x)[i * 2 + 1];
    s16x8 o;
    o[0] = (short)f2bf(a.x); o[1] = (short)f2bf(a.y);
    o[2] = (short)f2bf(a.z); o[3] = (short)f2bf(a.w);
    o[4] = (short)f2bf(b.x); o[5] = (short)f2bf(b.y);
    o[6] = (short)f2bf(b.z); o[7] = (short)f2bf(b.w);
    *(s16x8*)&xb[(size_t)i * 8] = o;
}

// ---------------------------------------------------------------------------
// RoPE cos/sin table [t][0..63]=cos, [t][64..127]=sin; bias from attention_mask
// ---------------------------------------------------------------------------
__global__ __launch_bounds__(256)
void build_tabs(float* __restrict__ tab, float* __restrict__ bias,
                const int* __restrict__ amask) {
    const int i = blockIdx.x * 256 + threadIdx.x;
    if (i < T_ * 64) {
        const int t = i >> 6, f = i & 63;
        const float inv = __expf((float)f * (-0.14391156642478335f)); // -ln(1e4)/64
        float s, c;
        sincosf((float)t * inv, &s, &c);
        tab[t * 128 + f] = c;
        tab[t * 128 + 64 + f] = s;
    }
    if (i < B_ * T_) bias[i] = amask[i] ? 0.f : -__builtin_inff();
}

// ---------------------------------------------------------------------------
// RoPE apply (in-place, bf16), table-based, 4 freqs/thread.
// ---------------------------------------------------------------------------
template <int NH>
__global__ __launch_bounds__(256)
void rope_apply(us* __restrict__ x, const float* __restrict__ tab, int total4) {
    const int idx = blockIdx.x * 256 + threadIdx.x;
    if (idx >= total4) return;
    const int i0  = (idx & 15) << 2;
    const int rest = idx >> 4;
    const int h   = rest % NH;
    const int row = rest / NH;
    const int t   = row & (T_ - 1);
    const f32x4 c = *(const f32x4*)&tab[t * 128 + i0];
    const f32x4 s = *(const f32x4*)&tab[t * 128 + 64 + i0];
    const size_t base = (size_t)row * (NH * 128) + h * 128 + i0;
    ushort4 lo = *(ushort4*)&x[base];
    ushort4 hi = *(ushort4*)&x[base + 64];
    float x1[4] = {bf2f(lo.x), bf2f(lo.y), bf2f(lo.z), bf2f(lo.w)};
    float x2[4] = {bf2f(hi.x), bf2f(hi.y), bf2f(hi.z), bf2f(hi.w)};
    ushort4 olo, ohi;
    olo.x = f2bf(x1[0]*c[0] - x2[0]*s[0]); ohi.x = f2bf(x2[0]*c[0] + x1[0]*s[0]);
    olo.y = f2bf(x1[1]*c[1] - x2[1]*s[1]); ohi.y = f2bf(x2[1]*c[1] + x1[1]*s[1]);
    olo.z = f2bf(x1[2]*c[2] - x2[2]*s[2]); ohi.z = f2bf(x2[2]*c[2] + x1[2]*s[2]);
    olo.w = f2bf(x1[3]*c[3] - x2[3]*s[3]); ohi.w = f2bf(x2[3]*c[3] + x1[3]*s[3]);
    *(ushort4*)&x[base]      = olo;
    *(ushort4*)&x[base + 64] = ohi;
}

// ---------------------------------------------------------------------------
// bf16 MFMA GEMM: C[M][N] = A[M][K] * Bt[N][K]^T
// 128x128 tile, BK=32, 256 threads (4 waves, 2x2, each 64x64 = 4x4 frags).
// AF32: A source fp32, reg-staged+converted. Else bf16 via global_load_lds.
// OUTMODE: 0 = bf16 row-major, 1 = f32 row-major,
//          2 = fused KV (N=1024): cols 0..511 -> kb[BT][512] bf16,
//              cols 512..1023 -> vt[(b*HKV+kv)*128+d][T] bf16 (V transposed,
//              packed ushort4 stores along t)
// ---------------------------------------------------------------------------
template <bool AF32, int OUTMODE>
__global__ __launch_bounds__(256)
void gemm_bf16(const void* __restrict__ Ap, const us* __restrict__ Bt,
               void* __restrict__ Cp, int M, int N, int K) {
    __shared__ us As[128 * 32];
    __shared__ us Bs[128 * 32];

    const int tid  = threadIdx.x;
    const int lane = tid & 63;
    const int w    = tid >> 6;
    const int lrow = lane & 15;
    const int lhi  = lane >> 4;
    const int wm   = w >> 1;
    const int wn   = w & 1;
    const int mbase = blockIdx.y * 128;
    const int nbase = blockIdx.x * 128;

    f32x4 acc[4][4] = {};

    for (int k0 = 0; k0 < K; k0 += 32) {
        __syncthreads();
        if constexpr (AF32) {
            const float* A = (const float*)Ap;
#pragma unroll
            for (int i = 0; i < 2; ++i) {
                const int c   = tid * 2 + i;
                const int row = c >> 2, cc = c & 3;
                const float* src = A + (size_t)(mbase + row) * K + k0 + ((cc ^ (row & 3)) << 3);
                const float4 v0 = *(const float4*)src;
                const float4 v1 = *(const float4*)(src + 4);
                s16x8 o;
                o[0] = (short)f2bf(v0.x); o[1] = (short)f2bf(v0.y);
                o[2] = (short)f2bf(v0.z); o[3] = (short)f2bf(v0.w);
                o[4] = (short)f2bf(v1.x); o[5] = (short)f2bf(v1.y);
                o[6] = (short)f2bf(v1.z); o[7] = (short)f2bf(v1.w);
                *(s16x8*)&As[c * 8] = o;
            }
        } else {
            const us* A = (const us*)Ap;
#pragma unroll
            for (int i = 0; i < 2; ++i) {
                const int cb = i * 256 + w * 64;
                const int c  = cb + lane;
                const int row = c >> 2, cc = c & 3;
                gload16(A + (size_t)(mbase + row) * K + k0 + ((cc ^ (row & 3)) << 3),
                        &As[cb * 8]);
            }
        }
#pragma unroll
        for (int i = 0; i < 2; ++i) {
            const int cb = i * 256 + w * 64;
            const int c  = cb + lane;
            const int row = c >> 2, cc = c & 3;
            gload16(Bt + (size_t)(nbase + row) * K + k0 + ((cc ^ (row & 3)) << 3),
                    &Bs[cb * 8]);
        }
        __syncthreads();

        s16x8 af[4], bfv[4];
#pragma unroll
        for (int mi = 0; mi < 4; ++mi) {
            const int r = wm * 64 + mi * 16 + lrow;
            af[mi] = *(const s16x8*)&As[r * 32 + ((lhi ^ (r & 3)) << 3)];
        }
#pragma unroll
        for (int ni = 0; ni < 4; ++ni) {
            const int r = wn * 64 + ni * 16 + lrow;
            bfv[ni] = *(const s16x8*)&Bs[r * 32 + ((lhi ^ (r & 3)) << 3)];
        }
#pragma unroll
        for (int mi = 0; mi < 4; ++mi)
#pragma unroll
            for (int ni = 0; ni < 4; ++ni)
                acc[mi][ni] = __builtin_amdgcn_mfma_f32_16x16x32_bf16(
                    af[mi], bfv[ni], acc[mi][ni], 0, 0, 0);
    }

    // epilogue: D col = lane&15, row = (lane>>4)*4 + reg  [HW-verified]
#pragma unroll
    for (int mi = 0; mi < 4; ++mi) {
#pragma unroll
        for (int ni = 0; ni < 4; ++ni) {
            const int gm0 = mbase + wm * 64 + mi * 16 + lhi * 4;
            const int gn  = nbase + wn * 64 + ni * 16 + lrow;
            if constexpr (OUTMODE == 0) {
#pragma unroll
                for (int r = 0; r < 4; ++r)
                    ((us*)Cp)[(size_t)(gm0 + r) * N + gn] = f2bf(acc[mi][ni][r]);
            } else if constexpr (OUTMODE == 1) {
#pragma unroll
                for (int r = 0; r < 4; ++r)
                    ((float*)Cp)[(size_t)(gm0 + r) * N + gn] = acc[mi][ni][r];
            } else {
                if (gn < KVD_) {
#pragma unroll
                    for (int r = 0; r < 4; ++r)
                        ((us*)Cp)[(size_t)(gm0 + r) * KVD_ + gn] = f2bf(acc[mi][ni][r]);
                } else {
                    const int nv = gn - KVD_;
                    const int bb = gm0 >> 11, t = gm0 & (T_ - 1);
                    us* vt = (us*)Cp + (size_t)BT_ * KVD_;
                    ushort4 o4;
                    o4.x = f2bf(acc[mi][ni][0]); o4.y = f2bf(acc[mi][ni][1]);
                    o4.z = f2bf(acc[mi][ni][2]); o4.w = f2bf(acc[mi][ni][3]);
                    *(ushort4*)&vt[((size_t)(bb * HKV_ + (nv >> 7)) * 128 + (nv & 127)) * T_ + t] = o4;
                }
            }
        }
    }
}

// ---------------------------------------------------------------------------
// MFMA flash attention v3: swapped-QK^T, 2 q-subtiles/wave (32 q-rows),
// in-register softmax with defer-max, P routed via per-wave LDS scratch.
// Block = (q-tile 128, h, b), 4 waves. KVBLK = 64, K/V double-buffered via
// global_load_lds (XOR chunk swizzle both sides). 80 KB LDS -> 2 blocks/CU.
// ---------------------------------------------------------------------------
__global__ __launch_bounds__(256)
void attn_mfma3(const us* __restrict__ qg, const us* __restrict__ kg,
                const us* __restrict__ vtg, const float* __restrict__ bias,
                const int* __restrict__ causal_p, us* __restrict__ outg) {
    // K dbuf [2][8192] @0, V^T dbuf [2][8192] @16384, P [4 waves][2][1024] @32768
    __shared__ us lds[40960];

    const int qt = 15 - blockIdx.x;      // heavy-first dispatch (LPT balance)
    const int q0 = qt * 128;
    const int h  = blockIdx.y;
    const int b  = blockIdx.z;
    const int kvh = h >> 2;              // G = 4
    const int causal = *causal_p;
    const int tid  = threadIdx.x;
    const int lane = tid & 63;
    const int w    = tid >> 6;
    const int lrow = lane & 15, lhi = lane >> 4;

    auto stageKV = [&](int buf, int s0) {
        us* Kd = lds + buf * 8192;
        us* Vd = lds + 16384 + buf * 8192;
#pragma unroll
        for (int i = 0; i < 4; ++i) {          // K [64 kv][128 d], 16 chunks/row
            const int cb = i * 256 + w * 64;
            const int c  = cb + lane;
            const int row = c >> 4, cc = c & 15;
            gload16(kg + (size_t)(b * T_ + s0 + row) * KVD_ + kvh * HD_ + ((cc ^ (row & 7)) << 3),
                    Kd + cb * 8);
        }
#pragma unroll
        for (int i = 0; i < 4; ++i) {          // V^T [128 d][64 kv], 8 chunks/row
            const int cb = i * 256 + w * 64;
            const int c  = cb + lane;
            const int row = c >> 3, cc = c & 7;
            gload16(vtg + (size_t)((b * HKV_ + kvh) * 128 + row) * T_ + s0 + ((cc ^ (row & 7)) << 3),
                    Vd + cb * 8);
        }
    };

    // ---- stage Q [128][128]: rows 0..63 -> K buf1, rows 64..127 -> V buf1 ----
#pragma unroll
    for (int i = 0; i < 8; ++i) {
        const int cb = i * 256 + w * 64;
        const int c  = cb + lane;
        const int row = c >> 4, cc = c & 15;
        us* dst = (cb < 1024) ? (lds + 8192 + cb * 8) : (lds + 24576 + (cb - 1024) * 8);
        gload16(qg + (size_t)(b * T_ + q0 + row) * QD_ + h * HD_ + ((cc ^ (row & 7)) << 3),
                dst);
    }
    __syncthreads();

    // hoist Q fragments: wave w owns q-rows w*32 + s*16 + lrow, s=0,1
    s16x8 qf[2][4];
#pragma unroll
    for (int s = 0; s < 2; ++s) {
        const int qr = w * 32 + s * 16 + lrow;
        const us* Qsp = (w * 32 + s * 16 < 64) ? (lds + 8192 + qr * 128)
                                               : (lds + 24576 + (qr - 64) * 128);
#pragma unroll
        for (int kc = 0; kc < 4; ++kc)
            qf[s][kc] = *(const s16x8*)&Qsp[((kc * 4 + lhi) ^ (qr & 7)) << 3];
    }
    stageKV(0, 0);
    __syncthreads();   // all hoists done + buf0 staged

    f32x4 o[2][8] = {};
    float m_run[2] = {-__builtin_inff(), -__builtin_inff()};
    float l_run[2] = {0.f, 0.f};
    us* Pw = lds + 32768 + w * 2048;
    const int ntiles = (causal ? (q0 + 128) : T_) >> 6;
    const float rscale = 0.08838834764831845f;   // 1/sqrt(128)
    int cur = 0;

    for (int it = 0; it < ntiles; ++it) {
        const int s0 = it << 6;
        if (it + 1 < ntiles) stageKV(cur ^ 1, s0 + 64);

        const us* Kcur = lds + cur * 8192;
        const us* Vcur = lds + 16384 + cur * 8192;

        // ---- QK^T, both qsubs sharing each kf read ----
        f32x4 sf[2][4];
#pragma unroll
        for (int j = 0; j < 4; ++j) {
            f32x4 a0 = {0.f, 0.f, 0.f, 0.f}, a1 = {0.f, 0.f, 0.f, 0.f};
            const int kr = j * 16 + lrow;
#pragma unroll
            for (int kc = 0; kc < 4; ++kc) {
                const s16x8 kf = *(const s16x8*)&Kcur[kr * 128 + (((kc * 4 + lhi) ^ (kr & 7)) << 3)];
                a0 = __builtin_amdgcn_mfma_f32_16x16x32_bf16(kf, qf[0][kc], a0, 0, 0, 0);
                a1 = __builtin_amdgcn_mfma_f32_16x16x32_bf16(kf, qf[1][kc], a1, 0, 0, 0);
            }
            sf[0][j] = a0; sf[1][j] = a1;
        }

        const float* brow = bias + b * T_ + s0;
        f32x4 bv[4];
#pragma unroll
        for (int j = 0; j < 4; ++j)
            bv[j] = *(const f32x4*)&brow[j * 16 + lhi * 4];

        s16x8 pa[2][2];
#pragma unroll
        for (int s = 0; s < 2; ++s) {
            const int qp = q0 + w * 32 + s * 16 + lrow;
            const bool needc = causal && (s0 + 63 > q0 + w * 32 + s * 16);
            float x[4][4];
#pragma unroll
            for (int j = 0; j < 4; ++j)
#pragma unroll
                for (int r = 0; r < 4; ++r) {
                    float xv = sf[s][j][r] * rscale + bv[j][r];
                    if (needc && (s0 + j * 16 + lhi * 4 + r > qp)) xv = -__builtin_inff();
                    x[j][r] = xv;
                }

            float tmax = x[0][0];
#pragma unroll
            for (int j = 0; j < 4; ++j)
#pragma unroll
                for (int r = 0; r < 4; ++r) tmax = fmaxf(tmax, x[j][r]);
            tmax = fmaxf(tmax, __shfl_xor(tmax, 16));
            tmax = fmaxf(tmax, __shfl_xor(tmax, 32));

            // defer-max: skip rescale when max growth bounded (exp(x-m) <= e^8)
            const bool defer = (m_run[s] != -__builtin_inff()) &&
                               __all(tmax <= m_run[s] + 8.f);
            float corr = 1.f, ls = 0.f;
            float ps[4][4];
            if (defer) {
                const float mo = m_run[s];
#pragma unroll
                for (int j = 0; j < 4; ++j)
#pragma unroll
                    for (int r = 0; r < 4; ++r) { ps[j][r] = __expf(x[j][r] - mo); ls += ps[j][r]; }
            } else {
                const float mn = fmaxf(m_run[s], tmax);
                if (mn == -__builtin_inff()) {
#pragma unroll
                    for (int j = 0; j < 4; ++j)
#pragma unroll
                        for (int r = 0; r < 4; ++r) ps[j][r] = 0.f;
                } else {
                    corr = __expf(m_run[s] - mn);   // exp(-inf)=0 on first tile
#pragma unroll
                    for (int j = 0; j < 4; ++j)
#pragma unroll
                        for (int r = 0; r < 4; ++r) { ps[j][r] = __expf(x[j][r] - mn); ls += ps[j][r]; }
                }
                float co[4];
#pragma unroll
                for (int r = 0; r < 4; ++r) co[r] = __shfl(corr, lhi * 4 + r);
#pragma unroll
                for (int dc = 0; dc < 8; ++dc) {
                    o[s][dc][0] *= co[0]; o[s][dc][1] *= co[1];
                    o[s][dc][2] *= co[2]; o[s][dc][3] *= co[3];
                }
                m_run[s] = mn;
            }
            ls += __shfl_xor(ls, 16);
            ls += __shfl_xor(ls, 32);
            l_run[s] = l_run[s] * corr + ls;

            // ---- P -> LDS (XOR-swizzled), then read back as PV A-frags ----
            // holder (lrow,lhi) owns P[q=lrow][kv=16j+4*lhi+r]; write b64 per j
            us* Ps = Pw + s * 1024;
#pragma unroll
            for (int j = 0; j < 4; ++j) {
                uint2 wv;
                wv.x = pack2(ps[j][0], ps[j][1]);
                wv.y = pack2(ps[j][2], ps[j][3]);
                *(uint2*)&Ps[lrow * 64 + ((16 * j + 4 * lhi) ^ ((lrow & 7) << 3))] = wv;
            }
            // reader (lrow,lhi) needs P[q=lrow][kv=8*lhi..+7] (+32 for upper half)
            pa[s][0] = *(const s16x8*)&Ps[lrow * 64 + ((8 * lhi) ^ ((lrow & 7) << 3))];
            pa[s][1] = *(const s16x8*)&Ps[lrow * 64 + ((32 + 8 * lhi) ^ ((lrow & 7) << 3))];
        }

        // ---- PV: each vb read feeds both qsubs ----
#pragma unroll
        for (int dc = 0; dc < 8; ++dc) {
            const int vr = dc * 16 + lrow;
            const s16x8 vb0 = *(const s16x8*)&Vcur[vr * 64 + ((lhi ^ (vr & 7)) << 3)];
            const s16x8 vb1 = *(const s16x8*)&Vcur[vr * 64 + (((4 + lhi) ^ (vr & 7)) << 3)];
            o[0][dc] = __builtin_amdgcn_mfma_f32_16x16x32_bf16(pa[0][0], vb0, o[0][dc], 0, 0, 0);
            o[0][dc] = __builtin_amdgcn_mfma_f32_16x16x32_bf16(pa[0][1], vb1, o[0][dc], 0, 0, 0);
            o[1][dc] = __builtin_amdgcn_mfma_f32_16x16x32_bf16(pa[1][0], vb0, o[1][dc], 0, 0, 0);
            o[1][dc] = __builtin_amdgcn_mfma_f32_16x16x32_bf16(pa[1][1], vb1, o[1][dc], 0, 0, 0);
        }
        __syncthreads();
        cur ^= 1;
    }

    // ---- normalize + write (bf16, (b,t,h,d); in-place over Q is safe) ----
#pragma unroll
    for (int s = 0; s < 2; ++s) {
        float lq[4];
#pragma unroll
        for (int r = 0; r < 4; ++r) lq[r] = __shfl(l_run[s], lhi * 4 + r);
#pragma unroll
        for (int r = 0; r < 4; ++r) {
            const float invl = lq[r] > 0.f ? 1.0f / lq[r] : 0.f;
            const size_t base =
                (size_t)(b * T_ + q0 + w * 32 + s * 16 + lhi * 4 + r) * QD_ + h * HD_ + lrow;
#pragma unroll
            for (int dc = 0; dc < 8; ++dc)
                outg[base + dc * 16] = f2bf(o[s][dc][r] * invl);
        }
    }
}

// ---------------------------------------------------------------------------
// kernel_launch
// d_in: 0=x f32[B,T,D], 1=attention_mask i32[B,T], 2=causal i32[1],
//       3=wq f32[D,2048], 4=wk f32[D,512], 5=wv f32[D,512], 6=wo f32[D,D]
// ws (us units): wqt 4.19M | wkvt 2.10M | qb 8.39M | kb 2.10M | vt 2.10M |
//   tab(f32) 0.52M | bias(f32) 8K | xw: xb 8.39M (overlapped by wot) = 55.6MB
//   (fallback without xb: 47.2MB; round-5 proved ws >= 47MB path works)
// ---------------------------------------------------------------------------
extern "C" void kernel_launch(void* const* d_in, const int* in_sizes, int n_in,
                              void* d_out, int out_size, void* d_ws, size_t ws_size,
                              hipStream_t stream) {
    const float* x      = (const float*)d_in[0];
    const int*   amask  = (const int*)d_in[1];
    const int*   causal = (const int*)d_in[2];
    const float* wq     = (const float*)d_in[3];
    const float* wk     = (const float*)d_in[4];
    const float* wv     = (const float*)d_in[5];
    const float* wo     = (const float*)d_in[6];
    float* out = (float*)d_out;

    us* p    = (us*)d_ws;
    us* wqt  = p;  p += (size_t)QD_ * D_;        // 4,194,304
    us* wkvt = p;  p += (size_t)1024 * D_;       // 2,097,152 (wk; wv)
    us* qb   = p;  p += (size_t)BT_ * QD_;       // 8,388,608
    us* kb   = p;  p += (size_t)BT_ * KVD_;      // 2,097,152
    us* vt   = p;  p += (size_t)BT_ * KVD_;      // 2,097,152 (must follow kb!)
    float* tab  = (float*)p;  p += (size_t)T_ * 128 * 2;   // 524,288 us
    float* bias = (float*)p;  p += (size_t)B_ * T_ * 2;    // 8,192 us
    us* xw   = p;                                 // xb (8.39M us) / wot (4.19M us)

    const size_t need_xb = ((size_t)(p - (us*)d_ws) + (size_t)BT_ * D_) * sizeof(us);
    const bool useXB = ws_size >= need_xb;

    build_tabs<<<512, 256, 0, stream>>>(tab, bias, amask);
    wtrans<<<dim3(64, 64), 256, 0, stream>>>(wq, wqt, D_, QD_);
    wtrans<<<dim3(64, 16), 256, 0, stream>>>(wk, wkvt, D_, KVD_);
    wtrans<<<dim3(64, 16), 256, 0, stream>>>(wv, wkvt + (size_t)KVD_ * D_, D_, KVD_);

    if (useXB) {
        cvt_bf16<<<4096, 256, 0, stream>>>(x, xw, BT_ * D_ / 8);
        gemm_bf16<false, 0><<<dim3(16, 32), 256, 0, stream>>>(xw, wqt, qb, BT_, QD_, D_);
        gemm_bf16<false, 2><<<dim3(8, 32), 256, 0, stream>>>(xw, wkvt, kb, BT_, 1024, D_);
    } else {
        gemm_bf16<true, 0><<<dim3(16, 32), 256, 0, stream>>>(x, wqt, qb, BT_, QD_, D_);
        gemm_bf16<true, 2><<<dim3(8, 32), 256, 0, stream>>>(x, wkvt, kb, BT_, 1024, D_);
    }

    rope_apply<H_><<<4096, 256, 0, stream>>>(qb, tab, BT_ * H_ * 16);
    rope_apply<HKV_><<<1024, 256, 0, stream>>>(kb, tab, BT_ * HKV_ * 16);

    attn_mfma3<<<dim3(16, 16, 2), 256, 0, stream>>>(qb, kb, vt, bias, causal, qb);

    // wo transpose into xw (xb is dead by now if useXB)
    wtrans<<<dim3(64, 64), 256, 0, stream>>>(wo, xw, D_, D_);
    gemm_bf16<false, 1><<<dim3(16, 32), 256, 0, stream>>>(qb, xw, out, BT_, D_, D_);
}

// Round 7
// 440.005 us; speedup vs baseline: 1.0609x; 1.0609x over previous
//
#include <hip/hip_runtime.h>
#include <hip/hip_bf16.h>
#include <stdint.h>

// Problem constants: B=2, T=2048, D=2048, H=16, HKV=4, HD=128
#define B_    2
#define T_    2048
#define D_    2048
#define H_    16
#define HKV_  4
#define HD_   128
#define BT_   (B_ * T_)            // 4096
#define QD_   2048                 // H*HD
#define KVD_  512                  // HKV*HD

typedef float  f32x4 __attribute__((ext_vector_type(4)));
typedef short  s16x8 __attribute__((ext_vector_type(8)));   // 8 bf16 (4 VGPRs) MFMA operand
typedef unsigned short us;

__device__ __forceinline__ us f2bf(float f) {
    unsigned int u = __builtin_bit_cast(unsigned int, f);
    u += 0x7FFFu + ((u >> 16) & 1u);              // RNE (finite values only)
    return (us)(u >> 16);
}
__device__ __forceinline__ float bf2f(us s) {
    unsigned int u = ((unsigned int)s) << 16;
    return __builtin_bit_cast(float, u);
}
__device__ __forceinline__ unsigned pack2(float a, float b) {
    return (unsigned)f2bf(a) | ((unsigned)f2bf(b) << 16);
}

#define GLOBAL_AS __attribute__((address_space(1)))
#define LDS_AS    __attribute__((address_space(3)))

// async global->LDS, 16B per lane. LDS dest = wave-uniform base + lane*16.
__device__ __forceinline__ void gload16(const void* g, void* l) {
    __builtin_amdgcn_global_load_lds((const GLOBAL_AS uint32_t*)g,
                                     (LDS_AS uint32_t*)l, 16, 0, 0);
}

// ---------------------------------------------------------------------------
// Weight transpose+convert: w fp32 [K][N] -> wt bf16 [N][K]
// ---------------------------------------------------------------------------
__global__ __launch_bounds__(256)
void wtrans(const float* __restrict__ w, us* __restrict__ wt, int K, int N) {
    __shared__ float t[32][33];
    const int k0 = blockIdx.x * 32, n0 = blockIdx.y * 32;
    const int tid = threadIdx.x;
    const int r = tid >> 3, c4 = (tid & 7) << 2;
    const float4 v = *(const float4*)&w[(size_t)(k0 + r) * N + n0 + c4];
    t[r][c4 + 0] = v.x; t[r][c4 + 1] = v.y; t[r][c4 + 2] = v.z; t[r][c4 + 3] = v.w;
    __syncthreads();
    ushort4 o;
    o.x = f2bf(t[c4 + 0][r]); o.y = f2bf(t[c4 + 1][r]);
    o.z = f2bf(t[c4 + 2][r]); o.w = f2bf(t[c4 + 3][r]);
    *(ushort4*)&wt[(size_t)(n0 + r) * K + k0 + c4] = o;
}

// ---------------------------------------------------------------------------
// x fp32 -> bf16 (8 elems/thread)
// ---------------------------------------------------------------------------
__global__ __launch_bounds__(256)
void cvt_bf16(const float* __restrict__ x, us* __restrict__ xb, int n8) {
    const int i = blockIdx.x * 256 + threadIdx.x;
    if (i >= n8) return;
    const float4 a = ((const float4*)x)[i * 2];
    const float4 b = ((const float4*)x)[i * 2 + 1];
    s16x8 o;
    o[0] = (short)f2bf(a.x); o[1] = (short)f2bf(a.y);
    o[2] = (short)f2bf(a.z); o[3] = (short)f2bf(a.w);
    o[4] = (short)f2bf(b.x); o[5] = (short)f2bf(b.y);
    o[6] = (short)f2bf(b.z); o[7] = (short)f2bf(b.w);
    *(s16x8*)&xb[(size_t)i * 8] = o;
}

// ---------------------------------------------------------------------------
// RoPE cos/sin table [t][0..63]=cos, [t][64..127]=sin; bias from attention_mask
// ---------------------------------------------------------------------------
__global__ __launch_bounds__(256)
void build_tabs(float* __restrict__ tab, float* __restrict__ bias,
                const int* __restrict__ amask) {
    const int i = blockIdx.x * 256 + threadIdx.x;
    if (i < T_ * 64) {
        const int t = i >> 6, f = i & 63;
        const float inv = __expf((float)f * (-0.14391156642478335f)); // -ln(1e4)/64
        float s, c;
        sincosf((float)t * inv, &s, &c);
        tab[t * 128 + f] = c;
        tab[t * 128 + 64 + f] = s;
    }
    if (i < B_ * T_) bias[i] = amask[i] ? 0.f : -__builtin_inff();
}

// ---------------------------------------------------------------------------
// RoPE apply (in-place, bf16), table-based, 4 freqs/thread.
// ---------------------------------------------------------------------------
template <int NH>
__global__ __launch_bounds__(256)
void rope_apply(us* __restrict__ x, const float* __restrict__ tab, int total4) {
    const int idx = blockIdx.x * 256 + threadIdx.x;
    if (idx >= total4) return;
    const int i0  = (idx & 15) << 2;
    const int rest = idx >> 4;
    const int h   = rest % NH;
    const int row = rest / NH;
    const int t   = row & (T_ - 1);
    const f32x4 c = *(const f32x4*)&tab[t * 128 + i0];
    const f32x4 s = *(const f32x4*)&tab[t * 128 + 64 + i0];
    const size_t base = (size_t)row * (NH * 128) + h * 128 + i0;
    ushort4 lo = *(ushort4*)&x[base];
    ushort4 hi = *(ushort4*)&x[base + 64];
    float x1[4] = {bf2f(lo.x), bf2f(lo.y), bf2f(lo.z), bf2f(lo.w)};
    float x2[4] = {bf2f(hi.x), bf2f(hi.y), bf2f(hi.z), bf2f(hi.w)};
    ushort4 olo, ohi;
    olo.x = f2bf(x1[0]*c[0] - x2[0]*s[0]); ohi.x = f2bf(x2[0]*c[0] + x1[0]*s[0]);
    olo.y = f2bf(x1[1]*c[1] - x2[1]*s[1]); ohi.y = f2bf(x2[1]*c[1] + x1[1]*s[1]);
    olo.z = f2bf(x1[2]*c[2] - x2[2]*s[2]); ohi.z = f2bf(x2[2]*c[2] + x1[2]*s[2]);
    olo.w = f2bf(x1[3]*c[3] - x2[3]*s[3]); ohi.w = f2bf(x2[3]*c[3] + x1[3]*s[3]);
    *(ushort4*)&x[base]      = olo;
    *(ushort4*)&x[base + 64] = ohi;
}

// ---------------------------------------------------------------------------
// bf16 MFMA GEMM: C[M][N] = A[M][K] * Bt[N][K]^T
// 128x128 tile, BK=32, 256 threads (4 waves, 2x2, each 64x64 = 4x4 frags).
// Bijective XCD swizzle on the linearized block id (grids are %8==0).
// AF32: A source fp32, reg-staged+converted. Else bf16 via global_load_lds.
// OUTMODE: 0 = bf16 row-major, 1 = f32 row-major,
//          2 = fused KV (N=1024): cols 0..511 -> kb[BT][512] bf16,
//              cols 512..1023 -> vt[(b*HKV+kv)*128+d][T] bf16 (V transposed,
//              packed ushort4 stores along t)
// ---------------------------------------------------------------------------
template <bool AF32, int OUTMODE>
__global__ __launch_bounds__(256)
void gemm_bf16(const void* __restrict__ Ap, const us* __restrict__ Bt,
               void* __restrict__ Cp, int M, int N, int K) {
    __shared__ us As[128 * 32];
    __shared__ us Bs[128 * 32];

    const int tid  = threadIdx.x;
    const int lane = tid & 63;
    const int w    = tid >> 6;
    const int lrow = lane & 15;
    const int lhi  = lane >> 4;
    const int wm   = w >> 1;
    const int wn   = w & 1;

    // XCD-aware bijective swizzle (T1): nwg % 8 == 0 for all our launches
    const int gx  = gridDim.x;
    const int nwg = gx * gridDim.y;
    int lin = blockIdx.x + blockIdx.y * gx;
    lin = (lin & 7) * (nwg >> 3) + (lin >> 3);
    const int mbase = (lin / gx) * 128;
    const int nbase = (lin % gx) * 128;

    f32x4 acc[4][4] = {};

    for (int k0 = 0; k0 < K; k0 += 32) {
        __syncthreads();
        if constexpr (AF32) {
            const float* A = (const float*)Ap;
#pragma unroll
            for (int i = 0; i < 2; ++i) {
                const int c   = tid * 2 + i;
                const int row = c >> 2, cc = c & 3;
                const float* src = A + (size_t)(mbase + row) * K + k0 + ((cc ^ (row & 3)) << 3);
                const float4 v0 = *(const float4*)src;
                const float4 v1 = *(const float4*)(src + 4);
                s16x8 o;
                o[0] = (short)f2bf(v0.x); o[1] = (short)f2bf(v0.y);
                o[2] = (short)f2bf(v0.z); o[3] = (short)f2bf(v0.w);
                o[4] = (short)f2bf(v1.x); o[5] = (short)f2bf(v1.y);
                o[6] = (short)f2bf(v1.z); o[7] = (short)f2bf(v1.w);
                *(s16x8*)&As[c * 8] = o;
            }
        } else {
            const us* A = (const us*)Ap;
#pragma unroll
            for (int i = 0; i < 2; ++i) {
                const int cb = i * 256 + w * 64;
                const int c  = cb + lane;
                const int row = c >> 2, cc = c & 3;
                gload16(A + (size_t)(mbase + row) * K + k0 + ((cc ^ (row & 3)) << 3),
                        &As[cb * 8]);
            }
        }
#pragma unroll
        for (int i = 0; i < 2; ++i) {
            const int cb = i * 256 + w * 64;
            const int c  = cb + lane;
            const int row = c >> 2, cc = c & 3;
            gload16(Bt + (size_t)(nbase + row) * K + k0 + ((cc ^ (row & 3)) << 3),
                    &Bs[cb * 8]);
        }
        __syncthreads();

        s16x8 af[4], bfv[4];
#pragma unroll
        for (int mi = 0; mi < 4; ++mi) {
            const int r = wm * 64 + mi * 16 + lrow;
            af[mi] = *(const s16x8*)&As[r * 32 + ((lhi ^ (r & 3)) << 3)];
        }
#pragma unroll
        for (int ni = 0; ni < 4; ++ni) {
            const int r = wn * 64 + ni * 16 + lrow;
            bfv[ni] = *(const s16x8*)&Bs[r * 32 + ((lhi ^ (r & 3)) << 3)];
        }
        __builtin_amdgcn_s_setprio(1);
#pragma unroll
        for (int mi = 0; mi < 4; ++mi)
#pragma unroll
            for (int ni = 0; ni < 4; ++ni)
                acc[mi][ni] = __builtin_amdgcn_mfma_f32_16x16x32_bf16(
                    af[mi], bfv[ni], acc[mi][ni], 0, 0, 0);
        __builtin_amdgcn_s_setprio(0);
    }

    // epilogue: D col = lane&15, row = (lane>>4)*4 + reg  [HW-verified]
#pragma unroll
    for (int mi = 0; mi < 4; ++mi) {
#pragma unroll
        for (int ni = 0; ni < 4; ++ni) {
            const int gm0 = mbase + wm * 64 + mi * 16 + lhi * 4;
            const int gn  = nbase + wn * 64 + ni * 16 + lrow;
            if constexpr (OUTMODE == 0) {
#pragma unroll
                for (int r = 0; r < 4; ++r)
                    ((us*)Cp)[(size_t)(gm0 + r) * N + gn] = f2bf(acc[mi][ni][r]);
            } else if constexpr (OUTMODE == 1) {
#pragma unroll
                for (int r = 0; r < 4; ++r)
                    ((float*)Cp)[(size_t)(gm0 + r) * N + gn] = acc[mi][ni][r];
            } else {
                if (gn < KVD_) {
#pragma unroll
                    for (int r = 0; r < 4; ++r)
                        ((us*)Cp)[(size_t)(gm0 + r) * KVD_ + gn] = f2bf(acc[mi][ni][r]);
                } else {
                    const int nv = gn - KVD_;
                    const int bb = gm0 >> 11, t = gm0 & (T_ - 1);
                    us* vt = (us*)Cp + (size_t)BT_ * KVD_;
                    ushort4 o4;
                    o4.x = f2bf(acc[mi][ni][0]); o4.y = f2bf(acc[mi][ni][1]);
                    o4.z = f2bf(acc[mi][ni][2]); o4.w = f2bf(acc[mi][ni][3]);
                    *(ushort4*)&vt[((size_t)(bb * HKV_ + (nv >> 7)) * 128 + (nv & 127)) * T_ + t] = o4;
                }
            }
        }
    }
}

// ---------------------------------------------------------------------------
// MFMA flash attention v4 (round-5 structure + occupancy/catalog deltas):
// swapped-QK^T, in-register softmax (+defer-max), P via dest-side shfl.
// Block = (q-tile 64 heavy-first, h, b), 4 waves x 16 q-rows. KVBLK = 64.
// K double-buffered via global_load_lds; V SINGLE buffer, reg-staged
// prefetch (T14): issue global loads early, ds_write after post-PV barrier.
// 48 KB LDS -> 3 blocks/CU (was 2). setprio around MFMA clusters (T5).
// ---------------------------------------------------------------------------
__global__ __launch_bounds__(256)
void attn_mfma4(const us* __restrict__ qg, const us* __restrict__ kg,
                const us* __restrict__ vtg, const float* __restrict__ bias,
                const int* __restrict__ causal_p, us* __restrict__ outg) {
    __shared__ us lds[24576];   // K dbuf [2][8192] @0, V [8192] @16384

    const int qt = 31 - blockIdx.x;      // heavy-first (LPT packing)
    const int q0 = qt * 64;
    const int h  = blockIdx.y;
    const int b  = blockIdx.z;
    const int kvh = h >> 2;              // G = 4
    const int causal = *causal_p;
    const int tid  = threadIdx.x;
    const int lane = tid & 63;
    const int w    = tid >> 6;
    const int lrow = lane & 15, lhi = lane >> 4;

    auto stageK = [&](int buf, int s0) {
        us* Kd = lds + buf * 8192;
#pragma unroll
        for (int i = 0; i < 4; ++i) {          // K [64 kv][128 d], 16 chunks/row
            const int cb = i * 256 + w * 64;
            const int c  = cb + lane;
            const int row = c >> 4, cc = c & 15;
            gload16(kg + (size_t)(b * T_ + s0 + row) * KVD_ + kvh * HD_ + ((cc ^ (row & 7)) << 3),
                    Kd + cb * 8);
        }
    };
    // V^T [128 d][64 kv] prefetch into regs (4 x 16B per lane)
    auto loadV = [&](s16x8 vr[4], int s0) {
#pragma unroll
        for (int i = 0; i < 4; ++i) {
            const int c  = i * 256 + w * 64 + lane;
            const int row = c >> 3, cc = c & 7;
            vr[i] = *(const s16x8*)(vtg +
                (size_t)((b * HKV_ + kvh) * 128 + row) * T_ + s0 + ((cc ^ (row & 7)) << 3));
        }
    };
    auto writeV = [&](const s16x8 vr[4]) {
        us* Vd = lds + 16384;
#pragma unroll
        for (int i = 0; i < 4; ++i) {
            const int c = i * 256 + w * 64 + lane;
            *(s16x8*)&Vd[c * 8] = vr[i];
        }
    };

    // ---- stage Q into K-buf-1 region ----
#pragma unroll
    for (int i = 0; i < 4; ++i) {
        const int cb = i * 256 + w * 64;
        const int c  = cb + lane;
        const int row = c >> 4, cc = c & 15;
        gload16(qg + (size_t)(b * T_ + q0 + row) * QD_ + h * HD_ + ((cc ^ (row & 7)) << 3),
                lds + 8192 + cb * 8);
    }
    __syncthreads();

    // hoist Q fragments (wave w owns q-rows w*16 .. w*16+15)
    s16x8 qf[4];
    {
        const us* Qsp = lds + 8192;
        const int qr = w * 16 + lrow;
#pragma unroll
        for (int kc = 0; kc < 4; ++kc)
            qf[kc] = *(const s16x8*)&Qsp[qr * 128 + (((kc * 4 + lhi) ^ (qr & 7)) << 3)];
    }
    s16x8 vreg[4];
    stageK(0, 0);
    loadV(vreg, 0);
    __syncthreads();           // qf hoists done (all waves), K0 drained
    writeV(vreg);
    __syncthreads();           // V0 visible

    f32x4 o[8] = {};
    float m_run = -__builtin_inff();
    float l_run = 0.f;
    const int qp = q0 + w * 16 + lrow;     // softmax lane's q
    const int ntiles = (causal ? (q0 + 64) : T_) >> 6;
    const float rscale = 0.08838834764831845f;   // 1/sqrt(128)
    int cur = 0;

    for (int it = 0; it < ntiles; ++it) {
        const int s0 = it << 6;
        const bool more = (it + 1 < ntiles);
        if (more) { stageK(cur ^ 1, s0 + 64); loadV(vreg, s0 + 64); }

        const us* Kcur = lds + cur * 8192;
        const us* Vcur = lds + 16384;

        // ---- QK^T swapped: sf[j] = S^T[kv=j*16+lhi*4+r][q=w*16+lrow] ----
        f32x4 sf[4];
        __builtin_amdgcn_s_setprio(1);
#pragma unroll
        for (int j = 0; j < 4; ++j) {
            f32x4 s = {0.f, 0.f, 0.f, 0.f};
            const int kr = j * 16 + lrow;
#pragma unroll
            for (int kc = 0; kc < 4; ++kc) {
                const s16x8 kf = *(const s16x8*)&Kcur[kr * 128 + (((kc * 4 + lhi) ^ (kr & 7)) << 3)];
                s = __builtin_amdgcn_mfma_f32_16x16x32_bf16(kf, qf[kc], s, 0, 0, 0);
            }
            sf[j] = s;
        }
        __builtin_amdgcn_s_setprio(0);

        // ---- scale + bias + causal mask (all lane-local) ----
        const float* brow = bias + b * T_ + s0;
        f32x4 bv[4];
#pragma unroll
        for (int j = 0; j < 4; ++j)
            bv[j] = *(const f32x4*)&brow[j * 16 + lhi * 4];
        const bool needc = causal && (s0 + 63 > q0 + w * 16);
        float x[4][4];
#pragma unroll
        for (int j = 0; j < 4; ++j)
#pragma unroll
            for (int r = 0; r < 4; ++r) {
                float xv = sf[j][r] * rscale + bv[j][r];
                if (needc && (s0 + j * 16 + lhi * 4 + r > qp)) xv = -__builtin_inff();
                x[j][r] = xv;
            }

        // ---- in-register online softmax (16 vals/lane + 2 shfl) ----
        float tmax = x[0][0];
#pragma unroll
        for (int j = 0; j < 4; ++j)
#pragma unroll
            for (int r = 0; r < 4; ++r) tmax = fmaxf(tmax, x[j][r]);
        tmax = fmaxf(tmax, __shfl_xor(tmax, 16));
        tmax = fmaxf(tmax, __shfl_xor(tmax, 32));

        // defer-max (T13): skip corr+rescale when growth bounded (P <= e^8)
        const bool defer = (m_run != -__builtin_inff()) &&
                           __all(tmax <= m_run + 8.f);
        float corr = 1.f, ls = 0.f, ps[4][4];
        if (defer) {
            const float mo = m_run;
#pragma unroll
            for (int j = 0; j < 4; ++j)
#pragma unroll
                for (int r = 0; r < 4; ++r) { ps[j][r] = __expf(x[j][r] - mo); ls += ps[j][r]; }
        } else {
            const float mn = fmaxf(m_run, tmax);
            if (mn == -__builtin_inff()) {
#pragma unroll
                for (int j = 0; j < 4; ++j)
#pragma unroll
                    for (int r = 0; r < 4; ++r) ps[j][r] = 0.f;
            } else {
                corr = __expf(m_run - mn);   // exp(-inf)=0 on first tile
#pragma unroll
                for (int j = 0; j < 4; ++j)
#pragma unroll
                    for (int r = 0; r < 4; ++r) { ps[j][r] = __expf(x[j][r] - mn); ls += ps[j][r]; }
            }
            float co[4];
#pragma unroll
            for (int r = 0; r < 4; ++r) co[r] = __shfl(corr, lhi * 4 + r);
#pragma unroll
            for (int dc = 0; dc < 8; ++dc) {
                o[dc][0] *= co[0]; o[dc][1] *= co[1];
                o[dc][2] *= co[2]; o[dc][3] *= co[3];
            }
            m_run = mn;
        }
        ls += __shfl_xor(ls, 16);
        ls += __shfl_xor(ls, 32);
        l_run = l_run * corr + ls;

        // ---- build PV A-frags: shuffle both j-candidates, dest-side select ----
        const unsigned w00 = pack2(ps[0][0], ps[0][1]), w01 = pack2(ps[0][2], ps[0][3]);
        const unsigned w10 = pack2(ps[1][0], ps[1][1]), w11 = pack2(ps[1][2], ps[1][3]);
        const unsigned w20 = pack2(ps[2][0], ps[2][1]), w21 = pack2(ps[2][2], ps[2][3]);
        const unsigned w30 = pack2(ps[3][0], ps[3][1]), w31 = pack2(ps[3][2], ps[3][3]);
        int a0w[4], a1w[4];
#pragma unroll
        for (int m = 0; m < 4; ++m) {
            const int src = lrow + ((lhi & 1) << 5) + ((m & 2) << 3);
            const unsigned c0 = (m & 1) ? w01 : w00;
            const unsigned c1 = (m & 1) ? w11 : w10;
            const int t0 = __shfl((int)c0, src);
            const int t1 = __shfl((int)c1, src);
            a0w[m] = (lhi & 2) ? t1 : t0;
            const unsigned c2 = (m & 1) ? w21 : w20;
            const unsigned c3 = (m & 1) ? w31 : w30;
            const int t2 = __shfl((int)c2, src);
            const int t3 = __shfl((int)c3, src);
            a1w[m] = (lhi & 2) ? t3 : t2;
        }
        const s16x8 a0 = __builtin_bit_cast(s16x8, make_int4(a0w[0], a0w[1], a0w[2], a0w[3]));
        const s16x8 a1 = __builtin_bit_cast(s16x8, make_int4(a1w[0], a1w[1], a1w[2], a1w[3]));

        // ---- PV ----
        __builtin_amdgcn_s_setprio(1);
#pragma unroll
        for (int dc = 0; dc < 8; ++dc) {
            const int vr = dc * 16 + lrow;
            const s16x8 vb0 = *(const s16x8*)&Vcur[vr * 64 + ((lhi ^ (vr & 7)) << 3)];
            o[dc] = __builtin_amdgcn_mfma_f32_16x16x32_bf16(a0, vb0, o[dc], 0, 0, 0);
            const s16x8 vb1 = *(const s16x8*)&Vcur[vr * 64 + (((4 + lhi) ^ (vr & 7)) << 3)];
            o[dc] = __builtin_amdgcn_mfma_f32_16x16x32_bf16(a1, vb1, o[dc], 0, 0, 0);
        }
        __builtin_amdgcn_s_setprio(0);

        __syncthreads();           // PV reads done (all waves); K(it+1) drained
        if (more) writeV(vreg);    // overwrite V buffer with next tile
        __syncthreads();           // V(it+1) visible
        cur ^= 1;
    }

    // ---- normalize + write (bf16, (b,t,h,d); in-place over Q is safe) ----
    float lq[4];
#pragma unroll
    for (int r = 0; r < 4; ++r) lq[r] = __shfl(l_run, lhi * 4 + r);
#pragma unroll
    for (int r = 0; r < 4; ++r) {
        const float invl = lq[r] > 0.f ? 1.0f / lq[r] : 0.f;
        const size_t base = (size_t)(b * T_ + q0 + w * 16 + lhi * 4 + r) * QD_ + h * HD_ + lrow;
#pragma unroll
        for (int dc = 0; dc < 8; ++dc)
            outg[base + dc * 16] = f2bf(o[dc][r] * invl);
    }
}

// ---------------------------------------------------------------------------
// kernel_launch
// d_in: 0=x f32[B,T,D], 1=attention_mask i32[B,T], 2=causal i32[1],
//       3=wq f32[D,2048], 4=wk f32[D,512], 5=wv f32[D,512], 6=wo f32[D,D]
// ws (us units): wqt 4.19M | wkvt 2.10M | qb 8.39M | kb 2.10M | vt 2.10M |
//   tab(f32) 0.52M | bias(f32) 8K | xw: xb 8.39M (overlapped by wot) = 55.6MB
//   (fallback without xb: 47.2MB)
// ---------------------------------------------------------------------------
extern "C" void kernel_launch(void* const* d_in, const int* in_sizes, int n_in,
                              void* d_out, int out_size, void* d_ws, size_t ws_size,
                              hipStream_t stream) {
    const float* x      = (const float*)d_in[0];
    const int*   amask  = (const int*)d_in[1];
    const int*   causal = (const int*)d_in[2];
    const float* wq     = (const float*)d_in[3];
    const float* wk     = (const float*)d_in[4];
    const float* wv     = (const float*)d_in[5];
    const float* wo     = (const float*)d_in[6];
    float* out = (float*)d_out;

    us* p    = (us*)d_ws;
    us* wqt  = p;  p += (size_t)QD_ * D_;        // 4,194,304
    us* wkvt = p;  p += (size_t)1024 * D_;       // 2,097,152 (wk; wv)
    us* qb   = p;  p += (size_t)BT_ * QD_;       // 8,388,608
    us* kb   = p;  p += (size_t)BT_ * KVD_;      // 2,097,152
    us* vt   = p;  p += (size_t)BT_ * KVD_;      // 2,097,152 (must follow kb!)
    float* tab  = (float*)p;  p += (size_t)T_ * 128 * 2;   // 524,288 us
    float* bias = (float*)p;  p += (size_t)B_ * T_ * 2;    // 8,192 us
    us* xw   = p;                                 // xb (8.39M us) / wot (4.19M us)

    const size_t need_xb = ((size_t)(p - (us*)d_ws) + (size_t)BT_ * D_) * sizeof(us);
    const bool useXB = ws_size >= need_xb;

    build_tabs<<<512, 256, 0, stream>>>(tab, bias, amask);
    wtrans<<<dim3(64, 64), 256, 0, stream>>>(wq, wqt, D_, QD_);
    wtrans<<<dim3(64, 16), 256, 0, stream>>>(wk, wkvt, D_, KVD_);
    wtrans<<<dim3(64, 16), 256, 0, stream>>>(wv, wkvt + (size_t)KVD_ * D_, D_, KVD_);

    if (useXB) {
        cvt_bf16<<<4096, 256, 0, stream>>>(x, xw, BT_ * D_ / 8);
        gemm_bf16<false, 0><<<dim3(16, 32), 256, 0, stream>>>(xw, wqt, qb, BT_, QD_, D_);
        gemm_bf16<false, 2><<<dim3(8, 32), 256, 0, stream>>>(xw, wkvt, kb, BT_, 1024, D_);
    } else {
        gemm_bf16<true, 0><<<dim3(16, 32), 256, 0, stream>>>(x, wqt, qb, BT_, QD_, D_);
        gemm_bf16<true, 2><<<dim3(8, 32), 256, 0, stream>>>(x, wkvt, kb, BT_, 1024, D_);
    }

    rope_apply<H_><<<4096, 256, 0, stream>>>(qb, tab, BT_ * H_ * 16);
    rope_apply<HKV_><<<1024, 256, 0, stream>>>(kb, tab, BT_ * HKV_ * 16);

    attn_mfma4<<<dim3(32, 16, 2), 256, 0, stream>>>(qb, kb, vt, bias, causal, qb);

    // wo transpose into xw (xb is dead by now if useXB)
    wtrans<<<dim3(64, 64), 256, 0, stream>>>(wo, xw, D_, D_);
    gemm_bf16<false, 1><<<dim3(16, 32), 256, 0, stream>>>(qb, xw, out, BT_, D_, D_);
}